// Round 1
// 351.984 us; speedup vs baseline: 1.0159x; 1.0159x over previous
//
#include <hip/hip_runtime.h>
#include <hip/hip_bf16.h>

// Problem constants (B,T,S,D = 32,1024,1024,512)
#define B_ 32
#define T_ 1024
#define S_ 1024
#define D_ 512
#define M_ (B_*T_)       // 32768 GEMM rows
#define N_ D_            // 512  GEMM cols
#define K_ (2*D_)        // 1024 GEMM reduction

typedef __attribute__((ext_vector_type(8))) short bf16x8;  // 8 bf16 = 4 VGPRs
typedef __attribute__((ext_vector_type(4))) float f32x4;

__device__ inline unsigned short f2bf(float x) {
    union { float f; unsigned u; } v; v.f = x;
    unsigned r = v.u + 0x7FFFu + ((v.u >> 16) & 1u);   // RNE
    return (unsigned short)(r >> 16);
}

// pack 2 f32 -> 2 bf16 (RNE), packed in 32 bits
__device__ inline unsigned cvt2bf(float lo, float hi) {
#if __has_builtin(__builtin_amdgcn_cvt_pk_bf16_f32)
    typedef __attribute__((ext_vector_type(2))) __bf16 bf2;
    union { bf2 v; unsigned u; } r;
    r.v = __builtin_amdgcn_cvt_pk_bf16_f32(lo, hi);
    return r.u;
#else
    return (unsigned)f2bf(lo) | ((unsigned)f2bf(hi) << 16);
#endif
}

// fast tanh: 1 - 2/(e^{2x}+1) via hw exp2 + rcp. rel err ~1e-7, exact sat at +-1.
__device__ inline float fast_tanh(float x) {
#if __has_builtin(__builtin_amdgcn_exp2f) && __has_builtin(__builtin_amdgcn_rcpf)
    const float e = __builtin_amdgcn_exp2f(x * 2.885390082f);   // e^{2x}
    const float r = __builtin_amdgcn_rcpf(e + 1.0f);
    return 1.0f - 2.0f * r;
#else
    return tanhf(x);
#endif
}

// ---------------------------------------------------------------------------
// Kernel 1: alignment scan -> jbuf.
// ---------------------------------------------------------------------------
__global__ void align_kernel(const int* __restrict__ iv, int* __restrict__ jbuf) {
    const int b = blockIdx.x;          // 32 blocks x 64 threads
    const int lane = threadIdx.x;      // 16 tokens per lane
    const int* row = iv + b * T_;
    int f[16];
    int local = 0;
    const int t0 = lane * 16;
    #pragma unroll
    for (int q = 0; q < 16; ++q) {
        const int t = t0 + q;
        const int tok = row[t];
        const int fl = (t > 0 && (tok == 1 || tok == 2)) ? 1 : 0;
        f[q] = fl;
        local += fl;
    }
    int incl = local;
    #pragma unroll
    for (int off = 1; off < 64; off <<= 1) {
        const int up = __shfl_up(incl, off, 64);
        if (lane >= off) incl += up;
    }
    int run = incl - local;            // exclusive prefix at this lane's first token
    #pragma unroll
    for (int q = 0; q < 16; ++q) {
        const int t = t0 + q;
        run += f[q];
        int j;
        if (t == 0) {
            j = 0;                     // attn[b,0,0] = 1 always
        } else {
            j = t - run - 1;
            if (j < 0) j += S_;        // torch negative-index wrap
        }
        jbuf[b * T_ + t] = j;
    }
}

// ---------------------------------------------------------------------------
// Kernel 2: W [512,1024] f32 -> bf16
// ---------------------------------------------------------------------------
__global__ void pack_w(const float* __restrict__ W, unsigned short* __restrict__ Wbf) {
    const int idx = blockIdx.x * blockDim.x + threadIdx.x;   // N_*K_/8 threads
    const f32x4 a = ((const f32x4*)W)[idx * 2];
    const f32x4 c = ((const f32x4*)W)[idx * 2 + 1];
    union { bf16x8 v; unsigned u[4]; } pk;
    pk.u[0] = cvt2bf(a[0], a[1]); pk.u[1] = cvt2bf(a[2], a[3]);
    pk.u[2] = cvt2bf(c[0], c[1]); pk.u[3] = cvt2bf(c[2], c[3]);
    *(bf16x8*)(Wbf + (size_t)idx * 8) = pk.v;
}

// ---------------------------------------------------------------------------
// Kernel 3 (heterogeneous): blocks [0,512) attn one-hot; [512,1536) GEMM.
//
// R6 pipeline (counted-vmcnt, T3/T4-style): double-buffered As/Bs (64 KB),
// ONE raw s_barrier per K-step. Per iter i (p=i&1):
//   1. issue B DMA(i+1) -> Bs[p^1]          [4 loads, oldest]
//   2. issue A loads(i+2) -> regs            [8 loads]     (sched_barrier pins 1<2)
//   3. cvt regs A(i+1) -> As[p^1]            (compiler emits counted vmcnt for regs)
//   4. MFMA on As[p], Bs[p]
//   5. asm s_waitcnt vmcnt(8) lgkmcnt(0)     -> drains ONLY B(i+1); A(i+2) stays
//      in flight ACROSS the barrier (this is the whole point)
//   6. s_barrier
// Tail iters clamp ko and stage harmlessly so the vmcnt arithmetic stays
// uniform (clamped loads feed ds_writes -> not DCE'd).
// ---------------------------------------------------------------------------
#define BM 128
#define BN 128
#define BK 64
#define NIT (K_ / BK)                    // 16
#define KMAX (K_ - BK)                   // 960
#define NGEMM ((M_ / BM) * (N_ / BN))    // 1024
#define NATTN 512                        // 64 rows each

__global__ __launch_bounds__(256, 2)
void gemm_attn(const unsigned short* __restrict__ Wbf,
               const float* __restrict__ bias,
               float* __restrict__ out,
               float* __restrict__ attn,
               const float* __restrict__ ctx,
               const float* __restrict__ outp,
               const int* __restrict__ jbuf) {
    const int bx = blockIdx.x;
    const int tid = threadIdx.x;

    if (bx < NATTN) {
        // ---------------- attn one-hot: 64 rows per block ----------------
        const int m0 = bx * 64;
        #pragma unroll 4
        for (int r = 0; r < 64; ++r) {
            const int row = m0 + r;
            const int j = jbuf[row];               // broadcast load
            f32x4 v = {0.f, 0.f, 0.f, 0.f};
            if ((j >> 2) == tid) v[j & 3] = 1.0f;
            // streaming 128 MB: nontemporal, don't trash L2 (GEMM A-reuse lives there)
            __builtin_nontemporal_store(v, ((f32x4*)(attn + (size_t)row * S_)) + tid);
        }
        return;
    }

    // ---------------- GEMM tile ----------------
    __shared__ unsigned short As[2][BM * BK];   // 2 x 16 KB
    __shared__ unsigned short Bs[2][BN * BK];   // 2 x 16 KB

    const int gbx  = bx - NATTN;
    const int lane = tid & 63;
    const int wave = tid >> 6;
    const int wm = wave >> 1, wn = wave & 1;     // 2x2 waves -> 64x64 each
    const int l16 = lane & 15, quad = lane >> 4;

    const int bm = gbx & 255;                    // 256 m-tiles (XCD-affine)
    const int bn = gbx >> 8;                     // 4 n-tiles
    const int mBase = bm * BM;
    const int nBase = bn * BN;

    // A staging: chunk c = it*256+tid, row = it*32 + (tid>>3), kc = tid&7.
    const int kc   = tid & 7;
    const int rsub = tid >> 3;                   // 0..31
    const int sw   = kc ^ (rsub & 7);            // swizzle term, it-invariant
    const float* actx[4];
    const float* aout[4];
    #pragma unroll
    for (int it = 0; it < 4; ++it) {
        const int r = it * 32 + rsub;
        const int m = mBase + r;
        const int jm = jbuf[m];
        actx[it] = ctx + ((size_t)((m >> 10) * S_ + jm)) * D_ + kc * 8;
        aout[it] = outp + (size_t)m * D_ - D_ + kc * 8;     // add ko>=512
    }

    f32x4 acc[4][4] = {};
    f32x4 fa0[4][2], fa1[4][2];

#define LOAD_A(FA, KO) do {                                                    \
    const int _koa = (KO);                                                     \
    _Pragma("unroll")                                                          \
    for (int _it = 0; _it < 4; ++_it) {                                        \
        const float* _src = (_koa < D_) ? (actx[_it] + _koa) : (aout[_it] + _koa); \
        FA[_it][0] = ((const f32x4*)_src)[0];                                  \
        FA[_it][1] = ((const f32x4*)_src)[1];                                  \
    }                                                                          \
} while (0)

#define DMA_B(PP, KO) do {                                                     \
    const int _kob = (KO);                                                     \
    _Pragma("unroll")                                                          \
    for (int _it = 0; _it < 4; ++_it) {                                        \
        const int _chunk = _it * 256 + tid;                                    \
        const int _row = _chunk >> 3;                                          \
        const int _kcb = _chunk & 7;                                           \
        const int _gk8 = (_kcb ^ (_row & 7)) * 8;                              \
        const unsigned short* _gB = Wbf + (size_t)(nBase + _row) * K_ + _kob + _gk8; \
        __builtin_amdgcn_global_load_lds(                                      \
            (const __attribute__((address_space(1))) void*)_gB,                \
            (__attribute__((address_space(3))) void*)(&Bs[PP][_chunk * 8]), 16, 0, 0); \
    }                                                                          \
} while (0)

#define STAGE_A(PP, FA) do {                                                   \
    _Pragma("unroll")                                                          \
    for (int _it = 0; _it < 4; ++_it) {                                        \
        union { bf16x8 v; unsigned u[4]; } _pk;                                \
        _pk.u[0] = cvt2bf(FA[_it][0][0], FA[_it][0][1]);                       \
        _pk.u[1] = cvt2bf(FA[_it][0][2], FA[_it][0][3]);                       \
        _pk.u[2] = cvt2bf(FA[_it][1][0], FA[_it][1][1]);                       \
        _pk.u[3] = cvt2bf(FA[_it][1][2], FA[_it][1][3]);                       \
        *(bf16x8*)&As[PP][(_it * 256 + rsub * 8 + sw) * 8] = _pk.v;            \
    }                                                                          \
} while (0)

#define MFMA_PH(PP) do {                                                       \
    _Pragma("unroll")                                                          \
    for (int _ks = 0; _ks < 2; ++_ks) {                                        \
        bf16x8 _af[4], _bfr[4];                                                \
        _Pragma("unroll")                                                      \
        for (int _mt = 0; _mt < 4; ++_mt) {                                    \
            const int _r = wm * 64 + _mt * 16 + l16;                           \
            const int _q = _ks * 4 + quad;                                     \
            _af[_mt] = *(const bf16x8*)&As[PP][(_r * 8 + (_q ^ (_r & 7))) * 8]; \
        }                                                                      \
        _Pragma("unroll")                                                      \
        for (int _nt = 0; _nt < 4; ++_nt) {                                    \
            const int _r = wn * 64 + _nt * 16 + l16;                           \
            const int _q = _ks * 4 + quad;                                     \
            _bfr[_nt] = *(const bf16x8*)&Bs[PP][(_r * 8 + (_q ^ (_r & 7))) * 8]; \
        }                                                                      \
        _Pragma("unroll")                                                      \
        for (int _mt = 0; _mt < 4; ++_mt)                                      \
            _Pragma("unroll")                                                  \
            for (int _nt = 0; _nt < 4; ++_nt)                                  \
                acc[_mt][_nt] = __builtin_amdgcn_mfma_f32_16x16x32_bf16(       \
                    _af[_mt], _bfr[_nt], acc[_mt][_nt], 0, 0, 0);              \
    }                                                                          \
} while (0)

    // -------- prologue: establish steady state entering iter 0 --------
    // outstanding order must be: [B(0) (drained below)] then A(1) in flight.
    LOAD_A(fa0, 0);                            // A(0)
    DMA_B(0, 0);                               // B(0) -> Bs[0]
    __builtin_amdgcn_sched_barrier(0);
    LOAD_A(fa1, BK);                           // A(1), stays in flight
    __builtin_amdgcn_sched_barrier(0);
    STAGE_A(0, fa0);                           // auto-waits A(0) only
    asm volatile("s_waitcnt vmcnt(8) lgkmcnt(0)" ::: "memory");  // drain B(0)
    __builtin_amdgcn_sched_barrier(0);
    __builtin_amdgcn_s_barrier();

    #pragma unroll 1
    for (int i = 0; i < NIT; i += 2) {
        const int ko = i * BK;
        // ---- even sub-iter: compute buf0, stage buf1 ----
        DMA_B(1, ko + BK);                                         // B(i+1)
        __builtin_amdgcn_sched_barrier(0);
        {
            const int _ka = (ko + 2 * BK > KMAX) ? KMAX : ko + 2 * BK;
            LOAD_A(fa0, _ka);                                      // A(i+2)
        }
        __builtin_amdgcn_sched_barrier(0);
        STAGE_A(1, fa1);                                           // A(i+1) -> As[1]
        MFMA_PH(0);
        asm volatile("s_waitcnt vmcnt(8) lgkmcnt(0)" ::: "memory"); // drain B(i+1), keep A(i+2)
        __builtin_amdgcn_sched_barrier(0);
        __builtin_amdgcn_s_barrier();

        // ---- odd sub-iter: compute buf1, stage buf0 ----
        {
            const int _kb = (ko + 2 * BK > KMAX) ? KMAX : ko + 2 * BK;
            DMA_B(0, _kb);                                         // B(i+2)
        }
        __builtin_amdgcn_sched_barrier(0);
        {
            const int _kcl = (ko + 3 * BK > KMAX) ? KMAX : ko + 3 * BK;
            LOAD_A(fa1, _kcl);                                     // A(i+3)
        }
        __builtin_amdgcn_sched_barrier(0);
        STAGE_A(0, fa0);                                           // A(i+2) -> As[0]
        MFMA_PH(1);
        asm volatile("s_waitcnt vmcnt(8) lgkmcnt(0)" ::: "memory");
        __builtin_amdgcn_sched_barrier(0);
        __builtin_amdgcn_s_barrier();
    }

#undef LOAD_A
#undef DMA_B
#undef STAGE_A
#undef MFMA_PH

    // ---- epilogue: fast_tanh(acc + bias), fp32 nontemporal store
    #pragma unroll
    for (int nt = 0; nt < 4; ++nt) {
        const int n = nBase + wn * 64 + nt * 16 + l16;
        const float bv = bias[n];
        #pragma unroll
        for (int mt = 0; mt < 4; ++mt) {
            #pragma unroll
            for (int r = 0; r < 4; ++r) {
                const int m = mBase + wm * 64 + mt * 16 + quad * 4 + r;
                const float val = fast_tanh(acc[mt][nt][r] + bv);
                __builtin_nontemporal_store(val, &out[(size_t)m * N_ + n]);
            }
        }
    }
}

// ---------------------------------------------------------------------------
extern "C" void kernel_launch(void* const* d_in, const int* in_sizes, int n_in,
                              void* d_out, int out_size, void* d_ws, size_t ws_size,
                              hipStream_t stream) {
    const int*   iv   = (const int*)d_in[0];    // input_var [B,T]
    const float* outp = (const float*)d_in[1];  // output   [B,T,D]
    const float* ctx  = (const float*)d_in[2];  // context  [B,S,D]
    // d_in[3] = di (unused by reference body)
    const float* W    = (const float*)d_in[4];  // [D, 2D]
    const float* bias = (const float*)d_in[5];  // [D]

    float* out  = (float*)d_out;                       // [B,T,D]
    float* attn = out + (size_t)M_ * N_;               // [B,T,S]

    // workspace layout: j[M_] int32 | Wbf[N_*K_] bf16   (~1.1 MB total)
    int* jbuf = (int*)d_ws;
    unsigned short* Wbf = (unsigned short*)((char*)d_ws + (size_t)M_ * 4);

    align_kernel<<<B_, 64, 0, stream>>>(iv, jbuf);
    pack_w<<<(N_ * K_ / 8) / 256, 256, 0, stream>>>(W, Wbf);
    gemm_attn<<<NGEMM + NATTN, 256, 0, stream>>>(Wbf, bias, out, attn, ctx, outp, jbuf);
}